// Round 7
// baseline (15516.257 us; speedup 1.0000x reference)
//
#include <hip/hip_runtime.h>

#define TT 512
#define FF 16
#define HH 256
#define OUTLEN 64
#define NT 9          // K tiles of 32 -> K=288 (h 0..255, bias 256, x/inp 257..272, pad)
#define PITCH 296     // uH/uL row pitch in halfs; 2-way-max bank aliasing on A reads
#define ROWS 16       // batch rows per block -> 256 blocks, 1 per CU
#define NBLK (4096/ROWS)
#define NFRAG (NT*16*4*64)   // half8 fragments per phase = 36864 (589824 B)
//
// R7 = R4 tiers + FLAG-PIPELINED ENCODER (no barriers in the encoder loop).
//   R5/R6 post-mortem: barrier-count and tier-order changes are null because
//   the h all-to-all dependency serializes the MFMA and VALU PHASES globally
//   (MfmaUtil 42 + VALUBusy 34 = 76% busy, pipes alternating instead of
//   dual-issuing). But the dependency is TILE-grained: kt j of A(t) is
//   produced by waves 2j,2j+1 only. So: per-wave publish flags fl[w] in LDS;
//   consumers spin only on the 2 producers of the kt they're about to read,
//   at point of first use. With R4's tier order the cascade is:
//     S01 waits {10..13}, k01 waits {0..3}, S23 waits {14,15}+xf, PIN waits
//     {4..9} -- waves 4-9's VALU tail hides under everyone's first 48 MFMAs.
//   Skew self-limits at <1 step (h(t+1) write requires all flags >= t+1),
//   so double-buffered activations (parity ping-pong) make overwrite races
//   impossible. Decoder keeps barriers (true all-reduce there).
// B residency (4 tiers):
//   kt0 + kt1 g0..2 -> 112 KB LDS tier (R5's proven squeeze)
//   kt1 g3          -> pkx, loop-carried-pinned
//   kt2,3,4         -> pk, loop-carried-pinned (R4's proven mechanism)
//   kt5..8          -> streamed 256 KB/step, cross-step double buffer
// LDS: 4x9.25 (act dbuf) + 112 (Bt) + 1 (red) + flags = 150.1 KB.

typedef _Float16 half8 __attribute__((ext_vector_type(8)));
typedef float f32x4 __attribute__((ext_vector_type(4)));

// 1-ulp rcp instead of the ~10-instr exact-division sequence (no fast-math here)
__device__ __forceinline__ float fsig(float x) {
  return __builtin_amdgcn_rcpf(1.0f + __expf(-x));
}
__device__ __forceinline__ float ftanh(float x) { return 2.0f * fsig(x + x) - 1.0f; }

// frag half8 idx = ((kt*16 + w)*4 + g)*64 + lane
//   col = g*256 + w*16 + (lane&15);  k = kt*32 + (lane>>4)*8 + j
__global__ void prep_kernel(const float* __restrict__ eWih, const float* __restrict__ eWhh,
                            const float* __restrict__ eb,  const float* __restrict__ dWih,
                            const float* __restrict__ dWhh, const float* __restrict__ db,
                            _Float16* __restrict__ E, _Float16* __restrict__ D) {
  int idx = blockIdx.x * 256 + threadIdx.x;
  if (idx >= NFRAG * 8) return;
  int j    = idx & 7;
  int lane = (idx >> 3) & 63;
  int rest = idx >> 9;         // (kt*16 + w)*4 + g
  int g    = rest & 3;
  int wv   = (rest >> 2) & 15;
  int kt   = rest >> 6;
  int col  = g * 256 + wv * 16 + (lane & 15);
  int k    = kt * 32 + (lane >> 4) * 8 + j;
  float ve = 0.f, vd = 0.f;
  if (k < HH)        { ve = eWhh[col * HH + k]; vd = dWhh[col * HH + k]; }
  else if (k == HH)  { ve = eb[col];            vd = db[col]; }
  else if (k <= 272) { ve = eWih[col * FF + (k - 257)]; if (k == 257) vd = dWih[col]; }
  E[idx] = (_Float16)ve;
  D[idx] = (_Float16)vd;
}

// strm points at kt5 base. Prologue: kt5 -> bf[0], kt6 -> bf[1].
__device__ __forceinline__ void fill_bf(half8 (&bf)[2][4], const half8* __restrict__ strm) {
#pragma unroll
  for (int g = 0; g < 4; ++g) bf[0][g] = strm[0 * 4096 + g * 64];  // kt5
#pragma unroll
  for (int g = 0; g < 4; ++g) bf[1][g] = strm[1 * 4096 + g * 64];  // kt6
}

// pp points at kt2 base. Load kt2,3,4 for this wave's 64 gate columns.
__device__ __forceinline__ void fill_pk(half8 (&pk)[3][4], const half8* __restrict__ pp) {
#pragma unroll
  for (int i = 0; i < 3; ++i)
#pragma unroll
    for (int g = 0; g < 4; ++g) pk[i][g] = pp[i * 4096 + g * 64];
}

// Loop-carried register pin (R4's proven mechanism: FETCH 8.9GB -> 131MB).
#define PIN_ALL(pk, pkx)                                             \
  _Pragma("unroll")                                                  \
  for (int _i = 0; _i < 3; ++_i)                                     \
    _Pragma("unroll")                                                \
    for (int _g = 0; _g < 4; ++_g)                                   \
      asm volatile("" : "+v"(pk[_i][_g]));                           \
  asm volatile("" : "+v"(pkx));

// Spin until f[i0..i0+n) >= tgt. Uniform addresses -> broadcast LDS reads.
__device__ __forceinline__ void waitf(volatile int* f, int i0, int n, int tgt) {
#pragma unroll
  for (int i = 0; i < n; ++i)
    while (f[i0 + i] < tgt) {}
  asm volatile("" ::: "memory");   // no hoisting of A-reads above the spin
}

// ---- tiers (R4/R5 math, verbatim) ----
__device__ __forceinline__ void tier_s01(const _Float16* __restrict__ uHp,
                                         const _Float16* __restrict__ uLp,
                                         const half8* __restrict__ strm,
                                         half8 (&bf)[2][4], f32x4 (&acc)[4]) {
#pragma unroll
  for (int s = 0; s < 2; ++s) {      // kt = 5+s, consume bf[s]
    half8 AH = *(const half8*)(uHp + (5 + s) * 32);
    half8 AL = *(const half8*)(uLp + (5 + s) * 32);
#pragma unroll
    for (int g = 0; g < 4; ++g) acc[g] = __builtin_amdgcn_mfma_f32_16x16x32_f16(AH, bf[s][g], acc[g], 0, 0, 0);
#pragma unroll
    for (int g = 0; g < 4; ++g) acc[g] = __builtin_amdgcn_mfma_f32_16x16x32_f16(AL, bf[s][g], acc[g], 0, 0, 0);
    const half8* rp = strm + (s + 2) * 4096;   // refill kt7 / kt8
#pragma unroll
    for (int g = 0; g < 4; ++g) bf[s][g] = rp[g * 64];
  }
}

__device__ __forceinline__ void tier_k01(const _Float16* __restrict__ uHp,
                                         const _Float16* __restrict__ uLp,
                                         const half8* __restrict__ Btp0,
                                         const half8* __restrict__ Btp1,
                                         const half8 pkx, f32x4 (&acc)[4]) {
  {  // kt0 (LDS)
    half8 b[4];
#pragma unroll
    for (int g = 0; g < 4; ++g) b[g] = Btp0[g * 64];
    half8 AH = *(const half8*)(uHp);
    half8 AL = *(const half8*)(uLp);
#pragma unroll
    for (int g = 0; g < 4; ++g) acc[g] = __builtin_amdgcn_mfma_f32_16x16x32_f16(AH, b[g], acc[g], 0, 0, 0);
#pragma unroll
    for (int g = 0; g < 4; ++g) acc[g] = __builtin_amdgcn_mfma_f32_16x16x32_f16(AL, b[g], acc[g], 0, 0, 0);
  }
  {  // kt1 (LDS g0..2 + pinned g3)
    half8 b[4];
#pragma unroll
    for (int g = 0; g < 3; ++g) b[g] = Btp1[g * 64];
    b[3] = pkx;
    half8 AH = *(const half8*)(uHp + 32);
    half8 AL = *(const half8*)(uLp + 32);
#pragma unroll
    for (int g = 0; g < 4; ++g) acc[g] = __builtin_amdgcn_mfma_f32_16x16x32_f16(AH, b[g], acc[g], 0, 0, 0);
#pragma unroll
    for (int g = 0; g < 4; ++g) acc[g] = __builtin_amdgcn_mfma_f32_16x16x32_f16(AL, b[g], acc[g], 0, 0, 0);
  }
}

__device__ __forceinline__ void tier_s23(const _Float16* __restrict__ uHp,
                                         const _Float16* __restrict__ uLp,
                                         const half8* __restrict__ strm,
                                         half8 (&bf)[2][4], f32x4 (&acc)[4]) {
#pragma unroll
  for (int s = 2; s < 4; ++s) {      // kt = 5+s, consume bf[s-2]
    half8 AH = *(const half8*)(uHp + (5 + s) * 32);
    half8 AL = *(const half8*)(uLp + (5 + s) * 32);
#pragma unroll
    for (int g = 0; g < 4; ++g) acc[g] = __builtin_amdgcn_mfma_f32_16x16x32_f16(AH, bf[s - 2][g], acc[g], 0, 0, 0);
#pragma unroll
    for (int g = 0; g < 4; ++g) acc[g] = __builtin_amdgcn_mfma_f32_16x16x32_f16(AL, bf[s - 2][g], acc[g], 0, 0, 0);
    const half8* rp = strm + (s - 2) * 4096;   // refill NEXT step's kt5 / kt6
#pragma unroll
    for (int g = 0; g < 4; ++g) bf[s - 2][g] = rp[g * 64];
  }
}

__device__ __forceinline__ void tier_pin(const _Float16* __restrict__ uHp,
                                         const _Float16* __restrict__ uLp,
                                         const half8 (&pk)[3][4], f32x4 (&acc)[4]) {
#pragma unroll
  for (int i = 0; i < 3; ++i) {      // kt2,3,4 -- zero B-memory traffic
    half8 AH = *(const half8*)(uHp + (2 + i) * 32);
    half8 AL = *(const half8*)(uLp + (2 + i) * 32);
#pragma unroll
    for (int g = 0; g < 4; ++g) acc[g] = __builtin_amdgcn_mfma_f32_16x16x32_f16(AH, pk[i][g], acc[g], 0, 0, 0);
#pragma unroll
    for (int g = 0; g < 4; ++g) acc[g] = __builtin_amdgcn_mfma_f32_16x16x32_f16(AL, pk[i][g], acc[g], 0, 0, 0);
  }
}

// Decoder matvec (barrier-gated, no flags).
__device__ __forceinline__ void mfma_step(const _Float16* __restrict__ uHp,
                                          const _Float16* __restrict__ uLp,
                                          const half8* __restrict__ Btp0,
                                          const half8* __restrict__ Btp1,
                                          const half8* __restrict__ strm,
                                          const half8 (&pk)[3][4],
                                          const half8 pkx,
                                          half8 (&bf)[2][4],
                                          f32x4 (&acc)[4]) {
#pragma unroll
  for (int g = 0; g < 4; ++g) acc[g] = (f32x4){0.f, 0.f, 0.f, 0.f};
  tier_s01(uHp, uLp, strm, bf, acc);
  tier_k01(uHp, uLp, Btp0, Btp1, pkx, acc);
  tier_s23(uHp, uLp, strm, bf, acc);
  tier_pin(uHp, uLp, pk, acc);
}

// 256 blocks x 1024 threads (16 waves, 4/SIMD). Block owns 16 batch rows and all
// 1024 gate columns. Wave w: unit = w*16+(lane&15); h-producer of kt(w/2)'s half.
__global__ __launch_bounds__(1024, 4) void seq2seq_kernel(
    const float* __restrict__ x,
    const _Float16* __restrict__ E, const _Float16* __restrict__ Dw,
    const float* __restrict__ Wout, const float* __restrict__ bout,
    float* __restrict__ out) {
  __shared__ _Float16 uHa[ROWS * PITCH];  // activation hi, parity 0
  __shared__ _Float16 uLa[ROWS * PITCH];  // activation lo, parity 0
  __shared__ _Float16 uHb[ROWS * PITCH];  // parity 1
  __shared__ _Float16 uLb[ROWS * PITCH];
  __shared__ half8 Bt[7168];              // 112 KB: kt0 full + kt1 g0..2
  __shared__ float red[ROWS * 16];        // 1 KB head partials [row][wave]
  __shared__ int fl[20];                  // [0..15] h publish, [16..19] x publish
  // 150.1 KB total -> 1 block/CU

  volatile int* vfl = fl;
  const int tid  = threadIdx.x;
  const int w    = tid >> 6;
  const int lane = tid & 63;
  const int quad = lane >> 4;
  const int l15  = lane & 15;
  const int b0   = blockIdx.x * ROWS;
  const int unit = w * 16 + l15;

  const half8* E8 = (const half8*)E;
  const half8* D8 = (const half8*)Dw;

  for (int i = tid; i < ROWS * PITCH; i += 1024) {
    uHa[i] = (_Float16)0.f; uLa[i] = (_Float16)0.f;
    uHb[i] = (_Float16)0.f; uLb[i] = (_Float16)0.f;
  }
  // Bt load with kt1 g3 squeezed out: slot i<4096 -> kt0; else kt1 g0..2.
  for (int i = tid; i < 7168; i += 1024)
    Bt[i] = E8[i < 4096 ? i : i + ((i - 4096) / 192) * 64];
  if (tid < 20) fl[tid] = 0;
  __syncthreads();

  const int   xr  = (tid >> 4) * PITCH + 257 + (tid & 15);
  const float* xp = x + ((long)(b0 + (tid >> 4)) * TT) * FF + (tid & 15);

  float xv = 0.f;
  if (tid < ROWS) { uHa[tid * PITCH + 256] = (_Float16)1.0f;   // bias-one col, both parities
                    uHb[tid * PITCH + 256] = (_Float16)1.0f; }
  if (tid < 256) {                      // stage x(0) into parity 0; prefetch x(1)
    xv = xp[0];
    _Float16 hs = (_Float16)xv;
    uHa[xr] = hs; uLa[xr] = (_Float16)(xv - (float)hs);
    xv = xp[FF];
  }

  const int aoff = l15 * PITCH + quad * 8;
  const half8* Btp0 = Bt + w * 256 + lane;          // kt0 frags [g*64]
  const half8* Btp1 = Bt + 4096 + w * 192 + lane;   // kt1 g0..2 frags [g*64]
  const half8* strm = E8 + 5 * 4096 + w * 256 + lane;  // kt5 base, streamed tier

  float cc[4] = {0.f, 0.f, 0.f, 0.f};
  const float wou = Wout[unit];
  const float bo  = bout[0];

  half8 pk[3][4];
  fill_pk(pk, E8 + 2 * 4096 + w * 256 + lane);      // pin kt2,3,4 (encoder)
  half8 pkx = E8[4096 + w * 256 + 192 + lane];      // pin kt1 g3
  half8 bf[2][4];
  fill_bf(bf, strm);                     // prologue: kt5,kt6 in flight
  __syncthreads();                       // bias + x(0) + flags visible

  _Float16 *cH = uHa, *cL = uLa, *nH = uHb, *nL = uLb;

  // ---------------- encoder: 512 steps, flag-pipelined, NO barriers ----------------
#pragma unroll 1
  for (int t = 0; t < TT; ++t) {
    PIN_ALL(pk, pkx);
    const _Float16* uHp = cH + aoff;
    const _Float16* uLp = cL + aoff;
    f32x4 acc[4];
#pragma unroll
    for (int g = 0; g < 4; ++g) acc[g] = (f32x4){0.f, 0.f, 0.f, 0.f};

    waitf(vfl, 10, 4, t);                // kt5,6 <- h units 160..223 (waves 10-13)
    tier_s01(uHp, uLp, strm, bf, acc);
    waitf(vfl, 0, 4, t);                 // kt0,1 <- units 0..63 (waves 0-3)
    tier_k01(uHp, uLp, Btp0, Btp1, pkx, acc);
    waitf(vfl, 14, 2, t);                // kt7 <- units 224..255 (waves 14,15)
    waitf(vfl, 16, 4, t);                // kt8 <- x(t) staged by waves 0-3
    tier_s23(uHp, uLp, strm, bf, acc);
    waitf(vfl, 4, 6, t);                 // kt2,3,4 <- units 64..159 (waves 4-9)
    tier_pin(uHp, uLp, pk, acc);

    if (tid < 256) {                     // stage x(t+1) into NXT, publish xf
      if (t < TT - 1) {
        _Float16 hs = (_Float16)xv;
        nH[xr] = hs; nL[xr] = (_Float16)(xv - (float)hs);
        if (t < TT - 2) xv = xp[(t + 2) * FF];
      }
      asm volatile("s_waitcnt lgkmcnt(0)" ::: "memory");
      if (lane == 0) vfl[16 + w] = t + 1;
    }

#pragma unroll
    for (int rg = 0; rg < 4; ++rg) {     // cell update -> write h(t) into NXT
      float ig = fsig(acc[0][rg]);
      float fg = fsig(acc[1][rg]);
      float gg = ftanh(acc[2][rg]);
      float og = fsig(acc[3][rg]);
      cc[rg] = fg * cc[rg] + ig * gg;
      float hv = og * ftanh(cc[rg]);
      const int m = quad * 4 + rg;
      _Float16 hs = (_Float16)hv;
      nH[m * PITCH + unit] = hs;
      nL[m * PITCH + unit] = (_Float16)(hv - (float)hs);
    }
    asm volatile("s_waitcnt lgkmcnt(0)" ::: "memory");
    if (lane == 0) vfl[w] = t + 1;       // publish h(t)

    _Float16* tp;
    tp = cH; cH = nH; nH = tp;
    tp = cL; cL = nL; nL = tp;
  }

  // ---- phase swap: decoder tier + pinned regs + stream base ----
  __syncthreads();                       // all encoder Bt/act reads done
  for (int i = tid; i < 7168; i += 1024)
    Bt[i] = D8[i < 4096 ? i : i + ((i - 4096) / 192) * 64];
  strm = D8 + 5 * 4096 + w * 256 + lane;
  fill_pk(pk, D8 + 2 * 4096 + w * 256 + lane);      // re-pin kt2,3,4 (decoder)
  pkx = D8[4096 + w * 256 + 192 + lane];
  fill_bf(bf, strm);                     // overwrite stale encoder kt5,kt6
  if (tid < ROWS) { cH[tid * PITCH + 257] = (_Float16)0.f;  // inp0 = 0 in CUR
                    cL[tid * PITCH + 257] = (_Float16)0.f; }
  // stale x cols 258..272 (both buffers): decoder weight rows there are zero.
  __syncthreads();

  // ---------------- decoder: 64 autoregressive steps (2 barriers: red dep) ----------------
#pragma unroll 1
  for (int td = 0; td < OUTLEN; ++td) {
    PIN_ALL(pk, pkx);
    f32x4 acc[4];
    mfma_step(cH + aoff, cL + aoff, Btp0, Btp1, strm, pk, pkx, bf, acc);

    float p[4];
#pragma unroll
    for (int rg = 0; rg < 4; ++rg) {     // cell update -> write h into NXT
      float ig = fsig(acc[0][rg]);
      float fg = fsig(acc[1][rg]);
      float gg = ftanh(acc[2][rg]);
      float og = fsig(acc[3][rg]);
      cc[rg] = fg * cc[rg] + ig * gg;
      float hv = og * ftanh(cc[rg]);
      const int m = quad * 4 + rg;
      _Float16 hs = (_Float16)hv;
      nH[m * PITCH + unit] = hs;
      nL[m * PITCH + unit] = (_Float16)(hv - (float)hs);
      p[rg] = hv * wou;
    }
    // head: sum this wave's 16 units (lanes of a quad share rows)
#pragma unroll
    for (int off = 1; off < 16; off <<= 1)
#pragma unroll
      for (int rg = 0; rg < 4; ++rg) p[rg] += __shfl_xor(p[rg], off, 64);
    if (l15 == 0) {
#pragma unroll
      for (int rg = 0; rg < 4; ++rg) red[(quad * 4 + rg) * 16 + w] = p[rg];
    }
    __syncthreads();                     // red + h-writes complete
    if (tid < ROWS) {                    // sum 16 waves -> out + feedback into NXT
      float s = bo;
#pragma unroll
      for (int u = 0; u < 16; ++u) s += red[tid * 16 + u];
      out[(long)(b0 + tid) * OUTLEN + td] = s;
      _Float16 hs = (_Float16)s;
      nH[tid * PITCH + 257] = hs;
      nL[tid * PITCH + 257] = (_Float16)(s - (float)hs);
    }
    __syncthreads();                     // inp visible before flip
    _Float16* tp;
    tp = cH; cH = nH; nH = tp;
    tp = cL; cL = nL; nL = tp;
  }
}

extern "C" void kernel_launch(void* const* d_in, const int* in_sizes, int n_in,
                              void* d_out, int out_size, void* d_ws, size_t ws_size,
                              hipStream_t stream) {
  const float* x    = (const float*)d_in[0];
  const float* eWih = (const float*)d_in[1];
  const float* eWhh = (const float*)d_in[2];
  const float* eb   = (const float*)d_in[3];
  const float* dWih = (const float*)d_in[4];
  const float* dWhh = (const float*)d_in[5];
  const float* db   = (const float*)d_in[6];
  const float* Wout = (const float*)d_in[7];
  const float* bout = (const float*)d_in[8];
  float* out = (float*)d_out;

  _Float16* E  = (_Float16*)d_ws;        // 589824 B
  _Float16* Dw = E + NFRAG * 8;          // 589824 B

  prep_kernel<<<dim3((NFRAG * 8 + 255) / 256), dim3(256), 0, stream>>>(
      eWih, eWhh, eb, dWih, dWhh, db, E, Dw);
  seq2seq_kernel<<<dim3(NBLK), dim3(1024), 0, stream>>>(
      x, E, Dw, Wout, bout, out);
}

// Round 8
// 5798.899 us; speedup vs baseline: 2.6757x; 2.6757x over previous
//
#include <hip/hip_runtime.h>

#define TT 512
#define FF 16
#define HH 256
#define OUTLEN 64
#define NT 9          // K tiles of 32 -> K=288 (h 0..255, bias 256, x/inp 257..272, pad)
#define PITCH 296     // uH/uL row pitch in halfs; 2-way-max bank aliasing on A reads
#define ROWS 16       // batch rows per block -> 256 blocks, 1 per CU
#define NBLK (4096/ROWS)
#define NFRAG (NT*16*4*64)   // half8 fragments per phase = 36864 (589824 B)
// R8 = R4 (proven 2899us: 2-barrier step, loop-carried pin, FETCH 131MB)
//      + kt5 joins the pinned tier (64 pinned regs, stream 192KB/step).
//   R7 post-mortem: flag-pipelining spilled ~26 regs/thread/step to scratch
//   (WRITE 53MB -> 31GB) -- spin loops + memory clobbers defeat the
//   allocator. Scheduling axis closed (R5 -4%, R6 +-0, R7 -5x).
// B residency (3 tiers):
//   kt0,1     -> 128 KB LDS tier
//   kt2,3,4,5 -> loop-carried-pinned (64 regs; PIN_PK "+v" each step --
//                R4's proven mechanism). GATE: WRITE_SIZE ~53MB = no spill.
//   kt6,7,8   -> streamed 192 KB/step, parity-free rotation:
//                S1 consume kt6 / refill kt8 (consumed S3, ~700cy lead)
//                S2 consume kt7 / refill NEXT kt7
//                S3 consume kt8 / refill NEXT kt6
//                PIN tail (32 MFMAs) covers next-step prefetch drain.

typedef _Float16 half8 __attribute__((ext_vector_type(8)));
typedef float f32x4 __attribute__((ext_vector_type(4)));

// 1-ulp rcp instead of the ~10-instr exact-division sequence (no fast-math here)
__device__ __forceinline__ float fsig(float x) {
  return __builtin_amdgcn_rcpf(1.0f + __expf(-x));
}
__device__ __forceinline__ float ftanh(float x) { return 2.0f * fsig(x + x) - 1.0f; }

// frag half8 idx = ((kt*16 + w)*4 + g)*64 + lane
//   col = g*256 + w*16 + (lane&15);  k = kt*32 + (lane>>4)*8 + j
__global__ void prep_kernel(const float* __restrict__ eWih, const float* __restrict__ eWhh,
                            const float* __restrict__ eb,  const float* __restrict__ dWih,
                            const float* __restrict__ dWhh, const float* __restrict__ db,
                            _Float16* __restrict__ E, _Float16* __restrict__ D) {
  int idx = blockIdx.x * 256 + threadIdx.x;
  if (idx >= NFRAG * 8) return;
  int j    = idx & 7;
  int lane = (idx >> 3) & 63;
  int rest = idx >> 9;         // (kt*16 + w)*4 + g
  int g    = rest & 3;
  int wv   = (rest >> 2) & 15;
  int kt   = rest >> 6;
  int col  = g * 256 + wv * 16 + (lane & 15);
  int k    = kt * 32 + (lane >> 4) * 8 + j;
  float ve = 0.f, vd = 0.f;
  if (k < HH)        { ve = eWhh[col * HH + k]; vd = dWhh[col * HH + k]; }
  else if (k == HH)  { ve = eb[col];            vd = db[col]; }
  else if (k <= 272) { ve = eWih[col * FF + (k - 257)]; if (k == 257) vd = dWih[col]; }
  E[idx] = (_Float16)ve;
  D[idx] = (_Float16)vd;
}

// strm points at kt6 base. Prologue: kt6 -> bf[0], kt7 -> bf[1].
__device__ __forceinline__ void fill_bf(half8 (&bf)[2][4], const half8* __restrict__ strm) {
#pragma unroll
  for (int g = 0; g < 4; ++g) bf[0][g] = strm[0 * 4096 + g * 64];  // kt6
#pragma unroll
  for (int g = 0; g < 4; ++g) bf[1][g] = strm[1 * 4096 + g * 64];  // kt7
}

// pp points at kt2 base. Load kt2,3,4,5 for this wave's 64 gate columns.
// Residency is enforced by the IN-LOOP pin (see step loops), not here.
__device__ __forceinline__ void fill_pk(half8 (&pk)[4][4], const half8* __restrict__ pp) {
#pragma unroll
  for (int i = 0; i < 4; ++i)
#pragma unroll
    for (int g = 0; g < 4; ++g) pk[i][g] = pp[i * 4096 + g * 64];
}

// Loop-carried register pin: consume-and-redefine every pinned fragment.
// Zero instructions; creates a cross-iteration VGPR dependence the
// allocator cannot break by re-loading. (R4: FETCH 8.9GB -> 131MB.)
#define PIN_PK(pk)                                                   \
  _Pragma("unroll")                                                  \
  for (int _i = 0; _i < 4; ++_i)                                     \
    _Pragma("unroll")                                                \
    for (int _g = 0; _g < 4; ++_g)                                   \
      asm volatile("" : "+v"(pk[_i][_g]));

// One step's matvec for this wave's 64 gate columns.
//   S1 (kt6; refill kt8) -> LDS tier kt0,1 -> S2 (kt7; refill next kt7) ->
//   S3 (kt8; refill next kt6) -> pinned kt2,3,4,5.
__device__ __forceinline__ void mfma_step(const _Float16* __restrict__ uHp,
                                          const _Float16* __restrict__ uLp,
                                          const half8* __restrict__ Btp,
                                          const half8* __restrict__ strm,
                                          const half8 (&pk)[4][4],
                                          half8 (&bf)[2][4],
                                          f32x4 (&acc)[4]) {
#pragma unroll
  for (int g = 0; g < 4; ++g) acc[g] = (f32x4){0.f, 0.f, 0.f, 0.f};

  {  // S1: kt6, consume bf[0]; refill bf[0] <- kt8 (consumed at S3)
    half8 AH = *(const half8*)(uHp + 6 * 32);
    half8 AL = *(const half8*)(uLp + 6 * 32);
#pragma unroll
    for (int g = 0; g < 4; ++g) acc[g] = __builtin_amdgcn_mfma_f32_16x16x32_f16(AH, bf[0][g], acc[g], 0, 0, 0);
#pragma unroll
    for (int g = 0; g < 4; ++g) acc[g] = __builtin_amdgcn_mfma_f32_16x16x32_f16(AL, bf[0][g], acc[g], 0, 0, 0);
    const half8* rp = strm + 2 * 4096;
#pragma unroll
    for (int g = 0; g < 4; ++g) bf[0][g] = rp[g * 64];
  }

#pragma unroll
  for (int kt = 0; kt < 2; ++kt) {   // LDS tier -- gives the kt8 refill its lead
    half8 b[4];
#pragma unroll
    for (int g = 0; g < 4; ++g) b[g] = Btp[kt * 4096 + g * 64];
    half8 AH = *(const half8*)(uHp + kt * 32);
    half8 AL = *(const half8*)(uLp + kt * 32);
#pragma unroll
    for (int g = 0; g < 4; ++g) acc[g] = __builtin_amdgcn_mfma_f32_16x16x32_f16(AH, b[g], acc[g], 0, 0, 0);
#pragma unroll
    for (int g = 0; g < 4; ++g) acc[g] = __builtin_amdgcn_mfma_f32_16x16x32_f16(AL, b[g], acc[g], 0, 0, 0);
  }

  {  // S2: kt7, consume bf[1]; refill bf[1] <- NEXT step's kt7
    half8 AH = *(const half8*)(uHp + 7 * 32);
    half8 AL = *(const half8*)(uLp + 7 * 32);
#pragma unroll
    for (int g = 0; g < 4; ++g) acc[g] = __builtin_amdgcn_mfma_f32_16x16x32_f16(AH, bf[1][g], acc[g], 0, 0, 0);
#pragma unroll
    for (int g = 0; g < 4; ++g) acc[g] = __builtin_amdgcn_mfma_f32_16x16x32_f16(AL, bf[1][g], acc[g], 0, 0, 0);
    const half8* rp = strm + 1 * 4096;
#pragma unroll
    for (int g = 0; g < 4; ++g) bf[1][g] = rp[g * 64];
  }

  {  // S3: kt8, consume bf[0]; refill bf[0] <- NEXT step's kt6
    half8 AH = *(const half8*)(uHp + 8 * 32);
    half8 AL = *(const half8*)(uLp + 8 * 32);
#pragma unroll
    for (int g = 0; g < 4; ++g) acc[g] = __builtin_amdgcn_mfma_f32_16x16x32_f16(AH, bf[0][g], acc[g], 0, 0, 0);
#pragma unroll
    for (int g = 0; g < 4; ++g) acc[g] = __builtin_amdgcn_mfma_f32_16x16x32_f16(AL, bf[0][g], acc[g], 0, 0, 0);
    const half8* rp = strm;
#pragma unroll
    for (int g = 0; g < 4; ++g) bf[0][g] = rp[g * 64];
  }

#pragma unroll
  for (int i = 0; i < 4; ++i) {      // pinned tier kt2,3,4,5 (zero memory traffic)
    half8 AH = *(const half8*)(uHp + (2 + i) * 32);
    half8 AL = *(const half8*)(uLp + (2 + i) * 32);
#pragma unroll
    for (int g = 0; g < 4; ++g) acc[g] = __builtin_amdgcn_mfma_f32_16x16x32_f16(AH, pk[i][g], acc[g], 0, 0, 0);
#pragma unroll
    for (int g = 0; g < 4; ++g) acc[g] = __builtin_amdgcn_mfma_f32_16x16x32_f16(AL, pk[i][g], acc[g], 0, 0, 0);
  }
}

// 256 blocks x 1024 threads (16 waves, 4/SIMD). Block owns 16 batch rows and all
// 1024 gate columns -> zero inter-block communication. Wave w: unit = w*16+(lane&15),
// rows m = quad*4+rg -> cc[4] lane-local across all 576 steps.
__global__ __launch_bounds__(1024, 4) void seq2seq_kernel(
    const float* __restrict__ x,
    const _Float16* __restrict__ E, const _Float16* __restrict__ Dw,
    const float* __restrict__ Wout, const float* __restrict__ bout,
    float* __restrict__ out) {
  __shared__ _Float16 uH[ROWS * PITCH];  // 9.25 KB activation hi [m][k]
  __shared__ _Float16 uL[ROWS * PITCH];  // 9.25 KB activation lo
  __shared__ half8 Bt[2 * 16 * 4 * 64];  // 128 KB  kt0,1 B tier (frag order)
  __shared__ float red[ROWS * 16];       // 1 KB   head partials [row][wave]
  // 147.5 KB total -> 1 block/CU

  const int tid  = threadIdx.x;
  const int w    = tid >> 6;
  const int lane = tid & 63;
  const int quad = lane >> 4;
  const int l15  = lane & 15;
  const int b0   = blockIdx.x * ROWS;
  const int unit = w * 16 + l15;

  const half8* E8 = (const half8*)E;
  const half8* D8 = (const half8*)Dw;

  for (int i = tid; i < ROWS * PITCH; i += 1024) { uH[i] = (_Float16)0.f; uL[i] = (_Float16)0.f; }
  for (int i = tid; i < 8192; i += 1024) Bt[i] = E8[i];   // kt0,1 tier (encoder)
  __syncthreads();
  if (tid < ROWS) uH[tid * PITCH + 256] = (_Float16)1.0f; // bias-one column

  const _Float16* uHp = uH + l15 * PITCH + quad * 8;
  const _Float16* uLp = uL + l15 * PITCH + quad * 8;
  const half8* Btp  = Bt + w * 256 + lane;                // [kt*4096 + g*64]
  const half8* strm = E8 + 6 * 4096 + w * 256 + lane;     // kt6 base, streamed tier

  float cc[4] = {0.f, 0.f, 0.f, 0.f};
  const float wou = Wout[unit];
  const float bo  = bout[0];
  const int   xr  = (tid >> 4) * PITCH + 257 + (tid & 15);
  const float* xp = x + ((long)(b0 + (tid >> 4)) * TT) * FF + (tid & 15);

  half8 pk[4][4];
  fill_pk(pk, E8 + 2 * 4096 + w * 256 + lane);  // load kt2,3,4,5 (encoder)
  half8 bf[2][4];
  fill_bf(bf, strm);                     // prologue: kt6,kt7 in flight

  // ---------------- encoder: 512 steps ----------------
  float xv = (tid < 256) ? xp[0] : 0.f;
#pragma unroll 1
  for (int t = 0; t < TT; ++t) {
    PIN_PK(pk);                          // loop-carried pin: kt2..5 stay resident
    if (tid < 256) {                     // stage x(t): 16 rows x 16 features, hi/lo
      _Float16 hs = (_Float16)xv;
      uH[xr] = hs; uL[xr] = (_Float16)(xv - (float)hs);
      if (t + 1 < TT) xv = xp[(t + 1) * FF];
    }
    __syncthreads();                     // h(t-1) + x(t) visible

    f32x4 acc[4];
    mfma_step(uHp, uLp, Btp, strm, pk, bf, acc);
    __syncthreads();                     // all A reads done before h overwrite

#pragma unroll
    for (int rg = 0; rg < 4; ++rg) {
      float ig = fsig(acc[0][rg]);
      float fg = fsig(acc[1][rg]);
      float gg = ftanh(acc[2][rg]);
      float og = fsig(acc[3][rg]);
      cc[rg] = fg * cc[rg] + ig * gg;
      float hv = og * ftanh(cc[rg]);
      const int m = quad * 4 + rg;
      _Float16 hs = (_Float16)hv;
      uH[m * PITCH + unit] = hs;
      uL[m * PITCH + unit] = (_Float16)(hv - (float)hs);
    }
  }

  // ---- phase swap: decoder tier + pinned regs + stream base ----
  __syncthreads();
  for (int i = tid; i < 8192; i += 1024) Bt[i] = D8[i];
  strm = D8 + 6 * 4096 + w * 256 + lane;
  fill_pk(pk, D8 + 2 * 4096 + w * 256 + lane);  // re-load kt2..5 (decoder)
  fill_bf(bf, strm);                     // overwrite stale encoder kt6,kt7
  if (tid < ROWS) { uH[tid * PITCH + 257] = (_Float16)0.f; uL[tid * PITCH + 257] = (_Float16)0.f; }
  // stale x cols 258..272: decoder weight rows there are zero -> no contribution

  // ---------------- decoder: 64 autoregressive steps ----------------
#pragma unroll 1
  for (int td = 0; td < OUTLEN; ++td) {
    PIN_PK(pk);                          // loop-carried pin (decoder weights)
    __syncthreads();                     // tier + h + inp visible

    f32x4 acc[4];
    mfma_step(uHp, uLp, Btp, strm, pk, bf, acc);
    __syncthreads();                     // reads done before overwrite

    float p[4];
#pragma unroll
    for (int rg = 0; rg < 4; ++rg) {
      float ig = fsig(acc[0][rg]);
      float fg = fsig(acc[1][rg]);
      float gg = ftanh(acc[2][rg]);
      float og = fsig(acc[3][rg]);
      cc[rg] = fg * cc[rg] + ig * gg;
      float hv = og * ftanh(cc[rg]);
      const int m = quad * 4 + rg;
      _Float16 hs = (_Float16)hv;
      uH[m * PITCH + unit] = hs;
      uL[m * PITCH + unit] = (_Float16)(hv - (float)hs);
      p[rg] = hv * wou;
    }
    // head: sum this wave's 16 units (lanes of a quad share rows)
#pragma unroll
    for (int off = 1; off < 16; off <<= 1)
#pragma unroll
      for (int rg = 0; rg < 4; ++rg) p[rg] += __shfl_xor(p[rg], off, 64);
    if (l15 == 0) {
#pragma unroll
      for (int rg = 0; rg < 4; ++rg) red[(quad * 4 + rg) * 16 + w] = p[rg];
    }
    __syncthreads();
    if (tid < ROWS) {                    // sum 16 waves -> out + autoregressive feedback
      float s = bo;
#pragma unroll
      for (int u = 0; u < 16; ++u) s += red[tid * 16 + u];
      out[(long)(b0 + tid) * OUTLEN + td] = s;
      _Float16 hs = (_Float16)s;
      uH[tid * PITCH + 257] = hs;
      uL[tid * PITCH + 257] = (_Float16)(s - (float)hs);
    }
  }
}

extern "C" void kernel_launch(void* const* d_in, const int* in_sizes, int n_in,
                              void* d_out, int out_size, void* d_ws, size_t ws_size,
                              hipStream_t stream) {
  const float* x    = (const float*)d_in[0];
  const float* eWih = (const float*)d_in[1];
  const float* eWhh = (const float*)d_in[2];
  const float* eb   = (const float*)d_in[3];
  const float* dWih = (const float*)d_in[4];
  const float* dWhh = (const float*)d_in[5];
  const float* db   = (const float*)d_in[6];
  const float* Wout = (const float*)d_in[7];
  const float* bout = (const float*)d_in[8];
  float* out = (float*)d_out;

  _Float16* E  = (_Float16*)d_ws;        // 589824 B
  _Float16* Dw = E + NFRAG * 8;          // 589824 B

  prep_kernel<<<dim3((NFRAG * 8 + 255) / 256), dim3(256), 0, stream>>>(
      eWih, eWhh, eb, dWih, dWhh, db, E, Dw);
  seq2seq_kernel<<<dim3(NBLK), dim3(1024), 0, stream>>>(
      x, E, Dw, Wout, bout, out);
}

// Round 9
// 3383.011 us; speedup vs baseline: 4.5865x; 1.7141x over previous
//
#include <hip/hip_runtime.h>

#define TT 512
#define FF 16
#define HH 256
#define OUTLEN 64
#define NT 9          // K tiles of 32 -> K=288 (h 0..255, bias 256, x/inp 257..272, pad)
#define PITCH 296     // uH/uL row pitch in halfs; 2-way-max bank aliasing on A reads
#define ROWS 16       // batch rows per block -> 256 blocks, 1 per CU
#define NBLK (4096/ROWS)
#define NFRAG (NT*16*4*64)   // half8 fragments per phase = 36864 (589824 B)
// R9 = R4 exactly (proven 2899us: 2-barrier step, 48-reg loop-carried pin,
//      FETCH 131MB) + LGKM-ONLY BARRIERS in the hot loops.
//   R8 post-mortem: 64-reg pin spilled (WRITE 53MB -> 10GB) -- 48 pinned is
//   the ceiling at 4 waves/SIMD. Reverted.
//   This round: __syncthreads() compiles to s_waitcnt vmcnt(0) lgkmcnt(0) +
//   s_barrier, which DRAINS our 8 in-flight cross-step refill loads at
//   barrier 2 every step -- the prefetch never survives a barrier. Both
//   barriers only guard LDS state (h/x ds_writes, A ds_reads); global
//   refills touch only VGPRs and may legally stay in flight. Replace with
//   {s_waitcnt lgkmcnt(0); s_barrier} -- same fence-point count as R4
//   (unlike R7's spin flags), so spill risk low. Refill L2 latency now
//   hides under cell-update + stage + next step's lead-in.
// B residency (3 tiers):
//   kt0,1   -> 128 KB LDS tier
//   kt2,3,4 -> loop-carried-pinned (48 regs; PIN_PK "+v" each step)
//   kt5..8  -> streamed 256 KB/step, cross-step double buffer
//              (S01: consume kt5,6 / refill kt7,8; S23: consume kt7,8 /
//               refill NEXT step's kt5,6; PIN tail covers the drain)

typedef _Float16 half8 __attribute__((ext_vector_type(8)));
typedef float f32x4 __attribute__((ext_vector_type(4)));

// 1-ulp rcp instead of the ~10-instr exact-division sequence (no fast-math here)
__device__ __forceinline__ float fsig(float x) {
  return __builtin_amdgcn_rcpf(1.0f + __expf(-x));
}
__device__ __forceinline__ float ftanh(float x) { return 2.0f * fsig(x + x) - 1.0f; }

// Workgroup barrier WITHOUT the vmcnt(0) drain: waits LDS ops only, leaves
// global (VGPR-destined) prefetch loads in flight across the barrier.
// Correct here because the only cross-wave shared state is LDS (+ 'out',
// which no thread ever reads back).
__device__ __forceinline__ void bar_lgkm() {
  asm volatile("s_waitcnt lgkmcnt(0)" ::: "memory");
  __builtin_amdgcn_s_barrier();
}

// frag half8 idx = ((kt*16 + w)*4 + g)*64 + lane
//   col = g*256 + w*16 + (lane&15);  k = kt*32 + (lane>>4)*8 + j
__global__ void prep_kernel(const float* __restrict__ eWih, const float* __restrict__ eWhh,
                            const float* __restrict__ eb,  const float* __restrict__ dWih,
                            const float* __restrict__ dWhh, const float* __restrict__ db,
                            _Float16* __restrict__ E, _Float16* __restrict__ D) {
  int idx = blockIdx.x * 256 + threadIdx.x;
  if (idx >= NFRAG * 8) return;
  int j    = idx & 7;
  int lane = (idx >> 3) & 63;
  int rest = idx >> 9;         // (kt*16 + w)*4 + g
  int g    = rest & 3;
  int wv   = (rest >> 2) & 15;
  int kt   = rest >> 6;
  int col  = g * 256 + wv * 16 + (lane & 15);
  int k    = kt * 32 + (lane >> 4) * 8 + j;
  float ve = 0.f, vd = 0.f;
  if (k < HH)        { ve = eWhh[col * HH + k]; vd = dWhh[col * HH + k]; }
  else if (k == HH)  { ve = eb[col];            vd = db[col]; }
  else if (k <= 272) { ve = eWih[col * FF + (k - 257)]; if (k == 257) vd = dWih[col]; }
  E[idx] = (_Float16)ve;
  D[idx] = (_Float16)vd;
}

// strm points at kt5 base. Prologue: kt5 -> bf[0], kt6 -> bf[1].
__device__ __forceinline__ void fill_bf(half8 (&bf)[2][4], const half8* __restrict__ strm) {
#pragma unroll
  for (int g = 0; g < 4; ++g) bf[0][g] = strm[0 * 4096 + g * 64];  // kt5
#pragma unroll
  for (int g = 0; g < 4; ++g) bf[1][g] = strm[1 * 4096 + g * 64];  // kt6
}

// pp points at kt2 base. Load kt2,3,4 for this wave's 64 gate columns.
// Residency is enforced by the IN-LOOP pin (see step loops), not here.
__device__ __forceinline__ void fill_pk(half8 (&pk)[3][4], const half8* __restrict__ pp) {
#pragma unroll
  for (int i = 0; i < 3; ++i)
#pragma unroll
    for (int g = 0; g < 4; ++g) pk[i][g] = pp[i * 4096 + g * 64];
}

// Loop-carried register pin: consume-and-redefine every pinned fragment.
// Zero instructions; creates a cross-iteration VGPR dependence the
// allocator cannot break by re-loading. (R4: FETCH 8.9GB -> 131MB.)
#define PIN_PK(pk)                                                   \
  _Pragma("unroll")                                                  \
  for (int _i = 0; _i < 3; ++_i)                                     \
    _Pragma("unroll")                                                \
    for (int _g = 0; _g < 4; ++_g)                                   \
      asm volatile("" : "+v"(pk[_i][_g]));

// One step's matvec for this wave's 64 gate columns.
//   stream s=0,1 (kt5,kt6; refill kt7,kt8) -> LDS tier kt0,1 ->
//   stream s=2,3 (kt7,kt8; refill NEXT step's kt5,kt6) -> pinned kt2,3,4.
__device__ __forceinline__ void mfma_step(const _Float16* __restrict__ uHp,
                                          const _Float16* __restrict__ uLp,
                                          const half8* __restrict__ Btp,
                                          const half8* __restrict__ strm,
                                          const half8 (&pk)[3][4],
                                          half8 (&bf)[2][4],
                                          f32x4 (&acc)[4]) {
#pragma unroll
  for (int g = 0; g < 4; ++g) acc[g] = (f32x4){0.f, 0.f, 0.f, 0.f};

#pragma unroll
  for (int s = 0; s < 2; ++s) {      // kt = 5+s, consume bf[s]
    half8 AH = *(const half8*)(uHp + (5 + s) * 32);
    half8 AL = *(const half8*)(uLp + (5 + s) * 32);
#pragma unroll
    for (int g = 0; g < 4; ++g) acc[g] = __builtin_amdgcn_mfma_f32_16x16x32_f16(AH, bf[s][g], acc[g], 0, 0, 0);
#pragma unroll
    for (int g = 0; g < 4; ++g) acc[g] = __builtin_amdgcn_mfma_f32_16x16x32_f16(AL, bf[s][g], acc[g], 0, 0, 0);
    {  // refill kt7 (s=0) / kt8 (s=1); consumed after the LDS tier below
      const half8* rp = strm + (s + 2) * 4096;
#pragma unroll
      for (int g = 0; g < 4; ++g) bf[s][g] = rp[g * 64];
    }
  }

#pragma unroll
  for (int kt = 0; kt < 2; ++kt) {   // LDS tier -- gives s=0,1 refills ~160cy lead
    half8 b[4];
#pragma unroll
    for (int g = 0; g < 4; ++g) b[g] = Btp[kt * 4096 + g * 64];
    half8 AH = *(const half8*)(uHp + kt * 32);
    half8 AL = *(const half8*)(uLp + kt * 32);
#pragma unroll
    for (int g = 0; g < 4; ++g) acc[g] = __builtin_amdgcn_mfma_f32_16x16x32_f16(AH, b[g], acc[g], 0, 0, 0);
#pragma unroll
    for (int g = 0; g < 4; ++g) acc[g] = __builtin_amdgcn_mfma_f32_16x16x32_f16(AL, b[g], acc[g], 0, 0, 0);
  }

#pragma unroll
  for (int s = 2; s < 4; ++s) {      // kt = 5+s, consume bf[s-2]
    half8 AH = *(const half8*)(uHp + (5 + s) * 32);
    half8 AL = *(const half8*)(uLp + (5 + s) * 32);
#pragma unroll
    for (int g = 0; g < 4; ++g) acc[g] = __builtin_amdgcn_mfma_f32_16x16x32_f16(AH, bf[s - 2][g], acc[g], 0, 0, 0);
#pragma unroll
    for (int g = 0; g < 4; ++g) acc[g] = __builtin_amdgcn_mfma_f32_16x16x32_f16(AL, bf[s - 2][g], acc[g], 0, 0, 0);
    {  // refill NEXT step's kt5 (s=2) / kt6 (s=3); drains under pinned tail
       // ...and now legally survives the step-end barrier (bar_lgkm).
      const half8* rp = strm + (s - 2) * 4096;
#pragma unroll
      for (int g = 0; g < 4; ++g) bf[s - 2][g] = rp[g * 64];
    }
  }

#pragma unroll
  for (int i = 0; i < 3; ++i) {      // pinned tier kt2,3,4 (zero memory traffic)
    half8 AH = *(const half8*)(uHp + (2 + i) * 32);
    half8 AL = *(const half8*)(uLp + (2 + i) * 32);
#pragma unroll
    for (int g = 0; g < 4; ++g) acc[g] = __builtin_amdgcn_mfma_f32_16x16x32_f16(AH, pk[i][g], acc[g], 0, 0, 0);
#pragma unroll
    for (int g = 0; g < 4; ++g) acc[g] = __builtin_amdgcn_mfma_f32_16x16x32_f16(AL, pk[i][g], acc[g], 0, 0, 0);
  }
}

// 256 blocks x 1024 threads (16 waves, 4/SIMD). Block owns 16 batch rows and all
// 1024 gate columns -> zero inter-block communication. Wave w: unit = w*16+(lane&15),
// rows m = quad*4+rg -> cc[4] lane-local across all 576 steps.
__global__ __launch_bounds__(1024, 4) void seq2seq_kernel(
    const float* __restrict__ x,
    const _Float16* __restrict__ E, const _Float16* __restrict__ Dw,
    const float* __restrict__ Wout, const float* __restrict__ bout,
    float* __restrict__ out) {
  __shared__ _Float16 uH[ROWS * PITCH];  // 9.25 KB activation hi [m][k]
  __shared__ _Float16 uL[ROWS * PITCH];  // 9.25 KB activation lo
  __shared__ half8 Bt[2 * 16 * 4 * 64];  // 128 KB  kt0,1 B tier (frag order)
  __shared__ float red[ROWS * 16];       // 1 KB   head partials [row][wave]
  // 147.5 KB total -> 1 block/CU

  const int tid  = threadIdx.x;
  const int w    = tid >> 6;
  const int lane = tid & 63;
  const int quad = lane >> 4;
  const int l15  = lane & 15;
  const int b0   = blockIdx.x * ROWS;
  const int unit = w * 16 + l15;

  const half8* E8 = (const half8*)E;
  const half8* D8 = (const half8*)Dw;

  for (int i = tid; i < ROWS * PITCH; i += 1024) { uH[i] = (_Float16)0.f; uL[i] = (_Float16)0.f; }
  for (int i = tid; i < 8192; i += 1024) Bt[i] = E8[i];   // kt0,1 tier (encoder)
  __syncthreads();
  if (tid < ROWS) uH[tid * PITCH + 256] = (_Float16)1.0f; // bias-one column

  const _Float16* uHp = uH + l15 * PITCH + quad * 8;
  const _Float16* uLp = uL + l15 * PITCH + quad * 8;
  const half8* Btp  = Bt + w * 256 + lane;                // [kt*4096 + g*64]
  const half8* strm = E8 + 5 * 4096 + w * 256 + lane;     // kt5 base, streamed tier

  float cc[4] = {0.f, 0.f, 0.f, 0.f};
  const float wou = Wout[unit];
  const float bo  = bout[0];
  const int   xr  = (tid >> 4) * PITCH + 257 + (tid & 15);
  const float* xp = x + ((long)(b0 + (tid >> 4)) * TT) * FF + (tid & 15);

  half8 pk[3][4];
  fill_pk(pk, E8 + 2 * 4096 + w * 256 + lane);  // load kt2,3,4 (encoder)
  half8 bf[2][4];
  fill_bf(bf, strm);                     // prologue: kt5,kt6 in flight

  // ---------------- encoder: 512 steps ----------------
  float xv = (tid < 256) ? xp[0] : 0.f;
#pragma unroll 1
  for (int t = 0; t < TT; ++t) {
    PIN_PK(pk);                          // loop-carried pin: kt2,3,4 stay resident
    if (tid < 256) {                     // stage x(t): 16 rows x 16 features, hi/lo
      _Float16 hs = (_Float16)xv;
      uH[xr] = hs; uL[xr] = (_Float16)(xv - (float)hs);
      if (t + 1 < TT) xv = xp[(t + 1) * FF];
    }
    bar_lgkm();                          // h(t-1) + x(t) visible (LDS only; x
                                         // prefetch load stays in flight)

    f32x4 acc[4];
    mfma_step(uHp, uLp, Btp, strm, pk, bf, acc);
    bar_lgkm();                          // all A ds_reads done before h
                                         // overwrite; refill loads NOT drained

#pragma unroll
    for (int rg = 0; rg < 4; ++rg) {
      float ig = fsig(acc[0][rg]);
      float fg = fsig(acc[1][rg]);
      float gg = ftanh(acc[2][rg]);
      float og = fsig(acc[3][rg]);
      cc[rg] = fg * cc[rg] + ig * gg;
      float hv = og * ftanh(cc[rg]);
      const int m = quad * 4 + rg;
      _Float16 hs = (_Float16)hv;
      uH[m * PITCH + unit] = hs;
      uL[m * PITCH + unit] = (_Float16)(hv - (float)hs);
    }
  }

  // ---- phase swap: decoder tier + pinned regs + stream base ----
  __syncthreads();
  for (int i = tid; i < 8192; i += 1024) Bt[i] = D8[i];
  strm = D8 + 5 * 4096 + w * 256 + lane;
  fill_pk(pk, D8 + 2 * 4096 + w * 256 + lane);  // re-load kt2,3,4 (decoder)
  fill_bf(bf, strm);                     // overwrite stale encoder kt5,kt6
  if (tid < ROWS) { uH[tid * PITCH + 257] = (_Float16)0.f; uL[tid * PITCH + 257] = (_Float16)0.f; }
  // stale x cols 258..272: decoder weight rows there are zero -> no contribution

  // ---------------- decoder: 64 autoregressive steps ----------------
#pragma unroll 1
  for (int td = 0; td < OUTLEN; ++td) {
    PIN_PK(pk);                          // loop-carried pin (decoder weights)
    bar_lgkm();                          // tier + h + inp visible

    f32x4 acc[4];
    mfma_step(uHp, uLp, Btp, strm, pk, bf, acc);
    bar_lgkm();                          // reads done before overwrite

    float p[4];
#pragma unroll
    for (int rg = 0; rg < 4; ++rg) {
      float ig = fsig(acc[0][rg]);
      float fg = fsig(acc[1][rg]);
      float gg = ftanh(acc[2][rg]);
      float og = fsig(acc[3][rg]);
      cc[rg] = fg * cc[rg] + ig * gg;
      float hv = og * ftanh(cc[rg]);
      const int m = quad * 4 + rg;
      _Float16 hs = (_Float16)hv;
      uH[m * PITCH + unit] = hs;
      uL[m * PITCH + unit] = (_Float16)(hv - (float)hs);
      p[rg] = hv * wou;
    }
    // head: sum this wave's 16 units (lanes of a quad share rows)
#pragma unroll
    for (int off = 1; off < 16; off <<= 1)
#pragma unroll
      for (int rg = 0; rg < 4; ++rg) p[rg] += __shfl_xor(p[rg], off, 64);
    if (l15 == 0) {
#pragma unroll
      for (int rg = 0; rg < 4; ++rg) red[(quad * 4 + rg) * 16 + w] = p[rg];
    }
    bar_lgkm();
    if (tid < ROWS) {                    // sum 16 waves -> out + autoregressive feedback
      float s = bo;
#pragma unroll
      for (int u = 0; u < 16; ++u) s += red[tid * 16 + u];
      out[(long)(b0 + tid) * OUTLEN + td] = s;
      _Float16 hs = (_Float16)s;
      uH[tid * PITCH + 257] = hs;
      uL[tid * PITCH + 257] = (_Float16)(s - (float)hs);
    }
  }
}

extern "C" void kernel_launch(void* const* d_in, const int* in_sizes, int n_in,
                              void* d_out, int out_size, void* d_ws, size_t ws_size,
                              hipStream_t stream) {
  const float* x    = (const float*)d_in[0];
  const float* eWih = (const float*)d_in[1];
  const float* eWhh = (const float*)d_in[2];
  const float* eb   = (const float*)d_in[3];
  const float* dWih = (const float*)d_in[4];
  const float* dWhh = (const float*)d_in[5];
  const float* db   = (const float*)d_in[6];
  const float* Wout = (const float*)d_in[7];
  const float* bout = (const float*)d_in[8];
  float* out = (float*)d_out;

  _Float16* E  = (_Float16*)d_ws;        // 589824 B
  _Float16* Dw = E + NFRAG * 8;          // 589824 B

  prep_kernel<<<dim3((NFRAG * 8 + 255) / 256), dim3(256), 0, stream>>>(
      eWih, eWhh, eb, dWih, dWhh, db, E, Dw);
  seq2seq_kernel<<<dim3(NBLK), dim3(1024), 0, stream>>>(
      x, E, Dw, Wout, bout, out);
}

// Round 10
// 2687.986 us; speedup vs baseline: 5.7724x; 1.2586x over previous
//
#include <hip/hip_runtime.h>

#define TT 512
#define FF 16
#define HH 256
#define OUTLEN 64
#define NT 9          // K tiles of 32 -> K=288 (h 0..255, bias 256, x/inp 257..272, pad)
#define PITCH 296     // uH/uL row pitch in halfs; 2-way-max bank aliasing on A reads
#define ROWS 16       // batch rows per block -> 256 blocks, 1 per CU
#define NBLK (4096/ROWS)
#define NFRAG (NT*16*4*64)   // half8 fragments per phase = 36864 (589824 B)
// R10 = R4 tiers, but 8 WAVES x 2 COLUMN-SLOTS (512 threads).
//   R9 post-mortem: lgkm-only barriers broke compiler scheduling (dur +17%,
//   FETCH 5x) -- back to __syncthreads. Six failed scheduling/pin-width
//   experiments; the wins were memory-tier changes. Last tier lever:
//   A-READ REDUNDANCY. In R4 all 16 waves read the SAME A fragments
//   (288 ds_read_b128/step/CU). Each wave now owns TWO wave-slots
//   (128 gate columns): one A-read feeds both -> 144 A-reads/step.
//   512 threads @ launch_bounds(512,2) unlocks the 256-VGPR budget
//   (m69: 8 waves/CU at <=256 regs), so the structure fits without
//   R8's 128-reg exact-fit spill: pk 96 + bf 32 + acc 32 + misc ~60.
// B residency (3 tiers), per wave-slot pair:
//   kt0,1   -> 128 KB LDS tier
//   kt2,3,4 -> loop-carried-pinned (96 regs = 3 kt x 2 slots x 4 frags)
//   kt5..8  -> streamed 256 KB/step/CU, single-set rotation: each refill
//              issued 16-32 MFMAs (310-620 cyc) before its consumption:
//              kt5 -> rf kt6 -> [kt0] -> kt6 -> rf kt7 -> [kt1] -> kt7 ->
//              rf kt8 -> [pin kt2,kt3] -> kt8 -> rf NEXT kt5 -> [pin kt4]
// GATES: VGPR ~200-250 (restructure took), WRITE ~53MB (no spill),
//        Occupancy ~25% (expected at 8 waves/CU).

typedef _Float16 half8 __attribute__((ext_vector_type(8)));
typedef float f32x4 __attribute__((ext_vector_type(4)));

// 1-ulp rcp instead of the ~10-instr exact-division sequence (no fast-math here)
__device__ __forceinline__ float fsig(float x) {
  return __builtin_amdgcn_rcpf(1.0f + __expf(-x));
}
__device__ __forceinline__ float ftanh(float x) { return 2.0f * fsig(x + x) - 1.0f; }

// frag half8 idx = ((kt*16 + w)*4 + g)*64 + lane
//   col = g*256 + w*16 + (lane&15);  k = kt*32 + (lane>>4)*8 + j
__global__ void prep_kernel(const float* __restrict__ eWih, const float* __restrict__ eWhh,
                            const float* __restrict__ eb,  const float* __restrict__ dWih,
                            const float* __restrict__ dWhh, const float* __restrict__ db,
                            _Float16* __restrict__ E, _Float16* __restrict__ D) {
  int idx = blockIdx.x * 256 + threadIdx.x;
  if (idx >= NFRAG * 8) return;
  int j    = idx & 7;
  int lane = (idx >> 3) & 63;
  int rest = idx >> 9;         // (kt*16 + w)*4 + g
  int g    = rest & 3;
  int wv   = (rest >> 2) & 15;
  int kt   = rest >> 6;
  int col  = g * 256 + wv * 16 + (lane & 15);
  int k    = kt * 32 + (lane >> 4) * 8 + j;
  float ve = 0.f, vd = 0.f;
  if (k < HH)        { ve = eWhh[col * HH + k]; vd = dWhh[col * HH + k]; }
  else if (k == HH)  { ve = eb[col];            vd = db[col]; }
  else if (k <= 272) { ve = eWih[col * FF + (k - 257)]; if (k == 257) vd = dWih[col]; }
  E[idx] = (_Float16)ve;
  D[idx] = (_Float16)vd;
}

// strm points at kt5 base for wave-slot 2w. bf[s][g] = frag of slot 2w+s.
__device__ __forceinline__ void refill_bf(half8 (&bf)[2][4], const half8* __restrict__ rp) {
#pragma unroll
  for (int s = 0; s < 2; ++s)
#pragma unroll
    for (int g = 0; g < 4; ++g) bf[s][g] = rp[s * 256 + g * 64];
}

// pp points at kt2 base for slot 2w. Load kt2,3,4 for both slots.
__device__ __forceinline__ void fill_pk(half8 (&pk)[3][2][4], const half8* __restrict__ pp) {
#pragma unroll
  for (int i = 0; i < 3; ++i)
#pragma unroll
    for (int s = 0; s < 2; ++s)
#pragma unroll
      for (int g = 0; g < 4; ++g) pk[i][s][g] = pp[i * 4096 + s * 256 + g * 64];
}

// Loop-carried register pin (R4's proven mechanism: FETCH 8.9GB -> 131MB).
#define PIN_PK(pk)                                                   \
  _Pragma("unroll")                                                  \
  for (int _i = 0; _i < 3; ++_i)                                     \
    _Pragma("unroll")                                                \
    for (int _s = 0; _s < 2; ++_s)                                   \
      _Pragma("unroll")                                              \
      for (int _g = 0; _g < 4; ++_g)                                 \
        asm volatile("" : "+v"(pk[_i][_s][_g]));

// One A-read pair (AH,AL) feeds BOTH column-slots: 32 MFMAs per kt per wave.
__device__ __forceinline__ void consume_bf(const _Float16* __restrict__ uHp,
                                           const _Float16* __restrict__ uLp,
                                           const int kt, const half8 (&bf)[2][4],
                                           f32x4 (&acc)[2][4]) {
  half8 AH = *(const half8*)(uHp + kt * 32);
  half8 AL = *(const half8*)(uLp + kt * 32);
#pragma unroll
  for (int s = 0; s < 2; ++s) {
#pragma unroll
    for (int g = 0; g < 4; ++g) acc[s][g] = __builtin_amdgcn_mfma_f32_16x16x32_f16(AH, bf[s][g], acc[s][g], 0, 0, 0);
#pragma unroll
    for (int g = 0; g < 4; ++g) acc[s][g] = __builtin_amdgcn_mfma_f32_16x16x32_f16(AL, bf[s][g], acc[s][g], 0, 0, 0);
  }
}

__device__ __forceinline__ void consume_lds(const _Float16* __restrict__ uHp,
                                            const _Float16* __restrict__ uLp,
                                            const int kt, const half8* __restrict__ Btp,
                                            f32x4 (&acc)[2][4]) {
  half8 AH = *(const half8*)(uHp + kt * 32);
  half8 AL = *(const half8*)(uLp + kt * 32);
#pragma unroll
  for (int s = 0; s < 2; ++s) {          // per-slot b[4] keeps transient pressure low
    half8 b[4];
#pragma unroll
    for (int g = 0; g < 4; ++g) b[g] = Btp[kt * 4096 + s * 256 + g * 64];
#pragma unroll
    for (int g = 0; g < 4; ++g) acc[s][g] = __builtin_amdgcn_mfma_f32_16x16x32_f16(AH, b[g], acc[s][g], 0, 0, 0);
#pragma unroll
    for (int g = 0; g < 4; ++g) acc[s][g] = __builtin_amdgcn_mfma_f32_16x16x32_f16(AL, b[g], acc[s][g], 0, 0, 0);
  }
}

__device__ __forceinline__ void consume_pin(const _Float16* __restrict__ uHp,
                                            const _Float16* __restrict__ uLp,
                                            const int i, const half8 (&pk)[3][2][4],
                                            f32x4 (&acc)[2][4]) {
  half8 AH = *(const half8*)(uHp + (2 + i) * 32);
  half8 AL = *(const half8*)(uLp + (2 + i) * 32);
#pragma unroll
  for (int s = 0; s < 2; ++s) {
#pragma unroll
    for (int g = 0; g < 4; ++g) acc[s][g] = __builtin_amdgcn_mfma_f32_16x16x32_f16(AH, pk[i][s][g], acc[s][g], 0, 0, 0);
#pragma unroll
    for (int g = 0; g < 4; ++g) acc[s][g] = __builtin_amdgcn_mfma_f32_16x16x32_f16(AL, pk[i][s][g], acc[s][g], 0, 0, 0);
  }
}

// One step's matvec for this wave's 128 gate columns (both slots).
__device__ __forceinline__ void mfma_step(const _Float16* __restrict__ uHp,
                                          const _Float16* __restrict__ uLp,
                                          const half8* __restrict__ Btp,
                                          const half8* __restrict__ strm,
                                          const half8 (&pk)[3][2][4],
                                          half8 (&bf)[2][4],
                                          f32x4 (&acc)[2][4]) {
#pragma unroll
  for (int s = 0; s < 2; ++s)
#pragma unroll
    for (int g = 0; g < 4; ++g) acc[s][g] = (f32x4){0.f, 0.f, 0.f, 0.f};

  consume_bf(uHp, uLp, 5, bf, acc);  refill_bf(bf, strm + 1 * 4096);  // -> kt6
  consume_lds(uHp, uLp, 0, Btp, acc);                                 // 310cy lead
  consume_bf(uHp, uLp, 6, bf, acc);  refill_bf(bf, strm + 2 * 4096);  // -> kt7
  consume_lds(uHp, uLp, 1, Btp, acc);
  consume_bf(uHp, uLp, 7, bf, acc);  refill_bf(bf, strm + 3 * 4096);  // -> kt8
  consume_pin(uHp, uLp, 0, pk, acc);
  consume_pin(uHp, uLp, 1, pk, acc);                                  // 620cy lead
  consume_bf(uHp, uLp, 8, bf, acc);  refill_bf(bf, strm);             // -> NEXT kt5
  consume_pin(uHp, uLp, 2, pk, acc); // + cell update covers next-kt5 drain
}

// 256 blocks x 512 threads (8 waves, 2/SIMD). Block owns 16 batch rows and all
// 1024 gate columns. Wave w owns slots 2w,2w+1 -> units (2w+s)*16 + l15.
__global__ __launch_bounds__(512, 2) void seq2seq_kernel(
    const float* __restrict__ x,
    const _Float16* __restrict__ E, const _Float16* __restrict__ Dw,
    const float* __restrict__ Wout, const float* __restrict__ bout,
    float* __restrict__ out) {
  __shared__ _Float16 uH[ROWS * PITCH];  // 9.25 KB activation hi [m][k]
  __shared__ _Float16 uL[ROWS * PITCH];  // 9.25 KB activation lo
  __shared__ half8 Bt[2 * 16 * 4 * 64];  // 128 KB  kt0,1 B tier (frag order)
  __shared__ float red[ROWS * 16];       // 1 KB   head partials [row][slot]
  // 147.5 KB total -> 1 block/CU

  const int tid  = threadIdx.x;
  const int w    = tid >> 6;             // 0..7
  const int lane = tid & 63;
  const int quad = lane >> 4;
  const int l15  = lane & 15;
  const int b0   = blockIdx.x * ROWS;

  const half8* E8 = (const half8*)E;
  const half8* D8 = (const half8*)Dw;

  for (int i = tid; i < ROWS * PITCH; i += 512) { uH[i] = (_Float16)0.f; uL[i] = (_Float16)0.f; }
  for (int i = tid; i < 8192; i += 512) Bt[i] = E8[i];    // kt0,1 tier (encoder)
  __syncthreads();
  if (tid < ROWS) uH[tid * PITCH + 256] = (_Float16)1.0f; // bias-one column

  const _Float16* uHp = uH + l15 * PITCH + quad * 8;
  const _Float16* uLp = uL + l15 * PITCH + quad * 8;
  const half8* Btp  = Bt + (2 * w) * 256 + lane;          // [kt*4096 + s*256 + g*64]
  const half8* strm = E8 + 5 * 4096 + (2 * w) * 256 + lane;  // kt5 base

  float cc[2][4] = {{0.f, 0.f, 0.f, 0.f}, {0.f, 0.f, 0.f, 0.f}};
  float wou[2];
  wou[0] = Wout[(2 * w) * 16 + l15];
  wou[1] = Wout[(2 * w + 1) * 16 + l15];
  const float bo  = bout[0];
  const int   xr  = (tid >> 4) * PITCH + 257 + (tid & 15);
  const float* xp = x + ((long)(b0 + (tid >> 4)) * TT) * FF + (tid & 15);

  half8 pk[3][2][4];
  fill_pk(pk, E8 + 2 * 4096 + (2 * w) * 256 + lane);  // load kt2,3,4 (encoder)
  half8 bf[2][4];
  refill_bf(bf, strm);                   // prologue: kt5 in flight

  // ---------------- encoder: 512 steps ----------------
  float xv = (tid < 256) ? xp[0] : 0.f;
#pragma unroll 1
  for (int t = 0; t < TT; ++t) {
    PIN_PK(pk);                          // loop-carried pin: kt2,3,4 stay resident
    if (tid < 256) {                     // stage x(t): 16 rows x 16 features, hi/lo
      _Float16 hs = (_Float16)xv;
      uH[xr] = hs; uL[xr] = (_Float16)(xv - (float)hs);
      if (t + 1 < TT) xv = xp[(t + 1) * FF];
    }
    __syncthreads();                     // h(t-1) + x(t) visible

    f32x4 acc[2][4];
    mfma_step(uHp, uLp, Btp, strm, pk, bf, acc);
    __syncthreads();                     // all A reads done before h overwrite

#pragma unroll
    for (int s = 0; s < 2; ++s) {
      const int unit = (2 * w + s) * 16 + l15;
#pragma unroll
      for (int rg = 0; rg < 4; ++rg) {
        float ig = fsig(acc[s][0][rg]);
        float fg = fsig(acc[s][1][rg]);
        float gg = ftanh(acc[s][2][rg]);
        float og = fsig(acc[s][3][rg]);
        cc[s][rg] = fg * cc[s][rg] + ig * gg;
        float hv = og * ftanh(cc[s][rg]);
        const int m = quad * 4 + rg;
        _Float16 hs = (_Float16)hv;
        uH[m * PITCH + unit] = hs;
        uL[m * PITCH + unit] = (_Float16)(hv - (float)hs);
      }
    }
  }

  // ---- phase swap: decoder tier + pinned regs + stream base ----
  __syncthreads();
  for (int i = tid; i < 8192; i += 512) Bt[i] = D8[i];
  strm = D8 + 5 * 4096 + (2 * w) * 256 + lane;
  fill_pk(pk, D8 + 2 * 4096 + (2 * w) * 256 + lane);  // re-load kt2,3,4 (decoder)
  refill_bf(bf, strm);                   // overwrite stale encoder kt5
  if (tid < ROWS) { uH[tid * PITCH + 257] = (_Float16)0.f; uL[tid * PITCH + 257] = (_Float16)0.f; }
  // stale x cols 258..272: decoder weight rows there are zero -> no contribution

  // ---------------- decoder: 64 autoregressive steps ----------------
#pragma unroll 1
  for (int td = 0; td < OUTLEN; ++td) {
    PIN_PK(pk);                          // loop-carried pin (decoder weights)
    __syncthreads();                     // tier + h + inp visible

    f32x4 acc[2][4];
    mfma_step(uHp, uLp, Btp, strm, pk, bf, acc);
    __syncthreads();                     // reads done before overwrite

    float p[2][4];
#pragma unroll
    for (int s = 0; s < 2; ++s) {
      const int unit = (2 * w + s) * 16 + l15;
#pragma unroll
      for (int rg = 0; rg < 4; ++rg) {
        float ig = fsig(acc[s][0][rg]);
        float fg = fsig(acc[s][1][rg]);
        float gg = ftanh(acc[s][2][rg]);
        float og = fsig(acc[s][3][rg]);
        cc[s][rg] = fg * cc[s][rg] + ig * gg;
        float hv = og * ftanh(cc[s][rg]);
        const int m = quad * 4 + rg;
        _Float16 hs = (_Float16)hv;
        uH[m * PITCH + unit] = hs;
        uL[m * PITCH + unit] = (_Float16)(hv - (float)hs);
        p[s][rg] = hv * wou[s];
      }
    }
    // head: sum each slot's 16 units (16-lane groups share rows)
#pragma unroll
    for (int off = 1; off < 16; off <<= 1)
#pragma unroll
      for (int s = 0; s < 2; ++s)
#pragma unroll
        for (int rg = 0; rg < 4; ++rg) p[s][rg] += __shfl_xor(p[s][rg], off, 64);
    if (l15 == 0) {
#pragma unroll
      for (int s = 0; s < 2; ++s)
#pragma unroll
        for (int rg = 0; rg < 4; ++rg) red[(quad * 4 + rg) * 16 + 2 * w + s] = p[s][rg];
    }
    __syncthreads();
    if (tid < ROWS) {                    // sum 16 slots -> out + autoregressive feedback
      float s = bo;
#pragma unroll
      for (int u = 0; u < 16; ++u) s += red[tid * 16 + u];
      out[(long)(b0 + tid) * OUTLEN + td] = s;
      _Float16 hs = (_Float16)s;
      uH[tid * PITCH + 257] = hs;
      uL[tid * PITCH + 257] = (_Float16)(s - (float)hs);
    }
  }
}

extern "C" void kernel_launch(void* const* d_in, const int* in_sizes, int n_in,
                              void* d_out, int out_size, void* d_ws, size_t ws_size,
                              hipStream_t stream) {
  const float* x    = (const float*)d_in[0];
  const float* eWih = (const float*)d_in[1];
  const float* eWhh = (const float*)d_in[2];
  const float* eb   = (const float*)d_in[3];
  const float* dWih = (const float*)d_in[4];
  const float* dWhh = (const float*)d_in[5];
  const float* db   = (const float*)d_in[6];
  const float* Wout = (const float*)d_in[7];
  const float* bout = (const float*)d_in[8];
  float* out = (float*)d_out;

  _Float16* E  = (_Float16*)d_ws;        // 589824 B
  _Float16* Dw = E + NFRAG * 8;          // 589824 B

  prep_kernel<<<dim3((NFRAG * 8 + 255) / 256), dim3(256), 0, stream>>>(
      eWih, eWhh, eb, dWih, dWhh, db, E, Dw);
  seq2seq_kernel<<<dim3(NBLK), dim3(512), 0, stream>>>(
      x, E, Dw, Wout, bout, out);
}